// Round 8
// baseline (167.889 us; speedup 1.0000x reference)
//
#include <hip/hip_runtime.h>
#include <math.h>

#define Bsz  2
#define Ntok 256
#define Ddim 512
#define Hdim 2048
#define Mrows 512

typedef __bf16 bf16_8 __attribute__((ext_vector_type(8)));
typedef __bf16 bf16_4 __attribute__((ext_vector_type(4)));
typedef float  f32x4_t __attribute__((ext_vector_type(4)));

// ---------------------------------------------------------------------------
// Prep kernel.
// [0,1152):    weight transpose+cast fp32 [K][N] -> bf16 [N][K], 64x64 tiles
// [1152,2176): distance partial sums (j split 4 ways), raw sums
// ---------------------------------------------------------------------------
struct PrepPtrs {
    const float* src[5];
    __bf16*      dst[5];
    const float* xv;
    const float* xa;
    float*       pv;    // [4][512] raw sums
    float*       pa;    // [4][512]
};

__global__ __launch_bounds__(256) void prep_kernel(PrepPtrs p) {
    __shared__ float tile[64][65];
    __shared__ float red[4][4];

    int blk = blockIdx.x;
    int tid = threadIdx.x;

    if (blk < 1152) {
        // ---- transpose+cast, 64x64 tile ----
        // W1v[512][2048], W1a[512][2048], Wmv[2048][512], Wma[2048][512], Wout[1024][512]
        const int Ks[5]  = {512, 512, 2048, 2048, 1024};
        const int Ns[5]  = {2048, 2048, 512, 512, 512};
        const int off[6] = {0, 256, 512, 768, 1024, 1152};
        int mi = 0;
        while (blk >= off[mi + 1]) ++mi;
        int local = blk - off[mi];
        int shift = (mi < 2) ? 5 : 3;         // n-tiles: 32 for W1*, 8 otherwise
        int bx = local & ((1 << shift) - 1);
        int by = local >> shift;
        const float* src = p.src[mi];
        __bf16*      dst = p.dst[mi];
        int K = Ks[mi], N = Ns[mi];
        int n0 = bx << 6, k0 = by << 6;

        int klb = tid >> 4, nl = (tid & 15) << 2;
#pragma unroll
        for (int pass = 0; pass < 4; ++pass) {
            int kl = (pass << 4) + klb;
            float4 v = *(const float4*)&src[(size_t)(k0 + kl) * N + n0 + nl];
            tile[kl][nl + 0] = v.x;
            tile[kl][nl + 1] = v.y;
            tile[kl][nl + 2] = v.z;
            tile[kl][nl + 3] = v.w;
        }
        __syncthreads();
        int nl2 = tid >> 2, kb = (tid & 3) << 2;
#pragma unroll
        for (int pass = 0; pass < 4; ++pass) {
            int kl2 = (pass << 4) + kb;
            bf16_4 o;
#pragma unroll
            for (int i = 0; i < 4; ++i) o[i] = (__bf16)tile[kl2 + i][nl2];
            *(bf16_4*)&dst[(size_t)(n0 + nl2) * K + k0 + kl2] = o;
        }
    } else {
        // ---- distance partials (verified R4-R7) ----
        int bx   = blk - 1152;
        int jc   = bx & 3;
        int g    = bx >> 2;
        int role = g >> 7;
        int b    = (g >> 6) & 1;
        int i0   = (g & 63) << 2;
        const float* Q    = role ? p.xa : p.xv;
        const float* S    = role ? p.xv : p.xa;
        float*       outp = role ? p.pa : p.pv;

        int d0 = tid << 1;
        const float* Qb = Q + ((size_t)b * Ntok + i0) * Ddim + d0;
        const float* Sb = S + ((size_t)b * Ntok + (jc << 6)) * Ddim + d0;

        float2 q[4];
#pragma unroll
        for (int r = 0; r < 4; ++r) q[r] = *(const float2*)(Qb + r * Ddim);

        float acc[4] = {0.f, 0.f, 0.f, 0.f};
#pragma unroll 4
        for (int j = 0; j < 64; ++j) {
            float2 s = *(const float2*)(Sb + (size_t)j * Ddim);
#pragma unroll
            for (int r = 0; r < 4; ++r)
                acc[r] += fabsf(q[r].x - s.x) + fabsf(q[r].y - s.y);
        }
        int lane = tid & 63, wv = tid >> 6;
#pragma unroll
        for (int r = 0; r < 4; ++r) {
            float v = acc[r];
#pragma unroll
            for (int off2 = 32; off2; off2 >>= 1) v += __shfl_down(v, off2);
            if (lane == 0) red[wv][r] = v;
        }
        __syncthreads();
        if (tid < 4) {
            float v = red[0][tid] + red[1][tid] + red[2][tid] + red[3][tid];
            outp[jc * Mrows + b * Ntok + i0 + tid] = v;
        }
    }
}

// ---------------------------------------------------------------------------
// Barrier-free register-fragment wave GEMM.
// Each WAVE computes a (16*MT)x(16*NT) output tile; A/B fragments are loaded
// straight from global as k-contiguous b128 reads (all operands L2-resident).
// No LDS, no __syncthreads -> no vmcnt(0) barrier drains; k-loop loads are
// independent so the compiler pipelines them freely.
// Fragment layout (verified R2-R7): lane=(quad,lrow); A[m0+i*16+lrow][quad*8+j],
// B[n0+j*16+lrow][quad*8+j]; C[m0+i*16+quad*4+r][n0+j*16+lrow].
// AFP32: A is fp32, scaled by mean-dist from pd partial sums, cast to bf16.
// ---------------------------------------------------------------------------
template <int GELU, int AFP32, int OUTBF16, int MT, int NT>
__device__ __forceinline__ void wave_gemm(const void* A, int lda,
                                          const __bf16* BT, int ldb,
                                          const float* bias, const float* pd,
                                          void* C, int ldc, int Kdim,
                                          int m0, int n0) {
    const int lane = threadIdx.x & 63;
    const int lrow = lane & 15, quad = lane >> 4;

    const float*  Af[MT];
    const __bf16* Ab[MT];
    float s[MT];
#pragma unroll
    for (int i = 0; i < MT; ++i) {
        int row = m0 + (i << 4) + lrow;
        if (AFP32) {
            Af[i] = (const float*)A + (size_t)row * lda + (quad << 3);
            s[i] = (pd[row] + pd[Mrows + row] + pd[2 * Mrows + row] +
                    pd[3 * Mrows + row]) * (1.0f / 256.0f);
        } else {
            Ab[i] = (const __bf16*)A + (size_t)row * lda + (quad << 3);
        }
    }
    const __bf16* Bp[NT];
#pragma unroll
    for (int j = 0; j < NT; ++j)
        Bp[j] = BT + (size_t)(n0 + (j << 4) + lrow) * ldb + (quad << 3);

    f32x4_t acc[MT][NT];
#pragma unroll
    for (int i = 0; i < MT; ++i)
#pragma unroll
        for (int j = 0; j < NT; ++j) acc[i][j] = {0.f, 0.f, 0.f, 0.f};

#pragma unroll 4
    for (int kt = 0; kt < Kdim; kt += 32) {
        bf16_8 b[NT], a[MT];
#pragma unroll
        for (int j = 0; j < NT; ++j) b[j] = *(const bf16_8*)(Bp[j] + kt);
#pragma unroll
        for (int i = 0; i < MT; ++i) {
            if (AFP32) {
                float4 f0 = *(const float4*)(Af[i] + kt);
                float4 f1 = *(const float4*)(Af[i] + kt + 4);
                a[i][0] = (__bf16)(f0.x * s[i]); a[i][1] = (__bf16)(f0.y * s[i]);
                a[i][2] = (__bf16)(f0.z * s[i]); a[i][3] = (__bf16)(f0.w * s[i]);
                a[i][4] = (__bf16)(f1.x * s[i]); a[i][5] = (__bf16)(f1.y * s[i]);
                a[i][6] = (__bf16)(f1.z * s[i]); a[i][7] = (__bf16)(f1.w * s[i]);
            } else {
                a[i] = *(const bf16_8*)(Ab[i] + kt);
            }
        }
#pragma unroll
        for (int i = 0; i < MT; ++i)
#pragma unroll
            for (int j = 0; j < NT; ++j)
                acc[i][j] = __builtin_amdgcn_mfma_f32_16x16x32_bf16(
                    a[i], b[j], acc[i][j], 0, 0, 0);
    }

#pragma unroll
    for (int j = 0; j < NT; ++j) {
        int col = n0 + (j << 4) + lrow;
        float bv = bias[col];
#pragma unroll
        for (int i = 0; i < MT; ++i) {
#pragma unroll
            for (int r = 0; r < 4; ++r) {
                int row = m0 + (i << 4) + (quad << 2) + r;
                float v = acc[i][j][r] + bv;
                if (GELU) v = 0.5f * v * (1.0f + erff(v * 0.70710678118654752f));
                if (OUTBF16)
                    ((__bf16*)C)[(size_t)row * ldc + col] = (__bf16)v;
                else
                    ((float*)C)[(size_t)row * ldc + col] = v;
            }
        }
    }
}

struct FPtrs {
    const float*  x[2];
    const __bf16* WT1[2];    // [2048][512]
    const float*  b1[2];
    const float*  pd[2];     // pv, pa partial dist sums [4][512]
    __bf16*       g1[2];     // [512][2048]
    const __bf16* WTm[2];    // [512][2048]
    const float*  bm[2];
    __bf16*       comb;      // [512][1024]
    const __bf16* WTout;     // [512][1024]
    const float*  bout;
    float*        out;       // [512][512] fp32
};

// GEMM1: g1[z] = gelu(diag(d)*x[z] @ W1[z] + b1[z]). 32x32 wave tiles.
// waves = 2 z * (16 mt * 64 nt) = 2048 -> 512 blocks.
__global__ __launch_bounds__(256) void gemm1_kernel(FPtrs p) {
    int gw = (blockIdx.x << 2) + (threadIdx.x >> 6);
    int z = gw >> 10, t = gw & 1023;
    int mt = t >> 6, nt = t & 63;
    wave_gemm<1, 1, 1, 2, 2>(p.x[z], Ddim, p.WT1[z], Ddim, p.b1[z], p.pd[z],
                             p.g1[z], Hdim, Ddim, mt << 5, nt << 5);
}

// GEMM2: comb[:, z*512 + n] = g1[z] @ Wm[z] + bm[z]. 16x16 wave tiles.
// waves = 2 z * (32 mt * 32 nt) = 2048 -> 512 blocks.
__global__ __launch_bounds__(256) void gemm2_kernel(FPtrs p) {
    int gw = (blockIdx.x << 2) + (threadIdx.x >> 6);
    int z = gw >> 10, t = gw & 1023;
    int mt = t >> 5, nt = t & 31;
    wave_gemm<0, 0, 1, 1, 1>(p.g1[z], Hdim, p.WTm[z], Hdim, p.bm[z], nullptr,
                             p.comb + (size_t)z * Ddim, 2 * Ddim, Hdim,
                             mt << 4, nt << 4);
}

// GEMM3: out = comb @ Wout + bout. 16x16 wave tiles.
// waves = 32 mt * 32 nt = 1024 -> 256 blocks.
__global__ __launch_bounds__(256) void gemm3_kernel(FPtrs p) {
    int gw = (blockIdx.x << 2) + (threadIdx.x >> 6);
    int mt = gw >> 5, nt = gw & 31;
    wave_gemm<0, 0, 0, 1, 1>(p.comb, 2 * Ddim, p.WTout, 2 * Ddim, p.bout,
                             nullptr, p.out, Ddim, 2 * Ddim,
                             mt << 4, nt << 4);
}

extern "C" void kernel_launch(void* const* d_in, const int* in_sizes, int n_in,
                              void* d_out, int out_size, void* d_ws, size_t ws_size,
                              hipStream_t stream) {
    const float* x_v  = (const float*)d_in[0];
    const float* x_a  = (const float*)d_in[1];
    const float* W1v  = (const float*)d_in[2];
    const float* b1v  = (const float*)d_in[3];
    const float* W1a  = (const float*)d_in[4];
    const float* b1a  = (const float*)d_in[5];
    const float* Wmv  = (const float*)d_in[6];
    const float* bmv  = (const float*)d_in[7];
    const float* Wma  = (const float*)d_in[8];
    const float* bma  = (const float*)d_in[9];
    const float* Wout = (const float*)d_in[10];
    const float* bout = (const float*)d_in[11];
    float* out = (float*)d_out;

    char* w = (char*)d_ws;
    auto alloc = [&](size_t bytes) {
        char* r = w;
        w += (bytes + 255) & ~(size_t)255;
        return (void*)r;
    };
    float*    pv    = (float*)alloc(4 * Mrows * 4);
    float*    pa    = (float*)alloc(4 * Mrows * 4);
    __bf16*   WT1v  = (__bf16*)alloc((size_t)Hdim * Ddim * 2);      // [2048][512]
    __bf16*   WT1a  = (__bf16*)alloc((size_t)Hdim * Ddim * 2);
    __bf16*   WTmv  = (__bf16*)alloc((size_t)Ddim * Hdim * 2);      // [512][2048]
    __bf16*   WTma  = (__bf16*)alloc((size_t)Ddim * Hdim * 2);
    __bf16*   WTout = (__bf16*)alloc((size_t)Ddim * 2 * Ddim * 2);  // [512][1024]
    __bf16*   g1v   = (__bf16*)alloc((size_t)Mrows * Hdim * 2);
    __bf16*   g1a   = (__bf16*)alloc((size_t)Mrows * Hdim * 2);
    __bf16*   comb  = (__bf16*)alloc((size_t)Mrows * 2 * Ddim * 2); // [512][1024]

    // 1) prep: 64x64 transpose+cast tiles + distance partials
    PrepPtrs pp;
    pp.src[0] = W1v;  pp.dst[0] = WT1v;
    pp.src[1] = W1a;  pp.dst[1] = WT1a;
    pp.src[2] = Wmv;  pp.dst[2] = WTmv;
    pp.src[3] = Wma;  pp.dst[3] = WTma;
    pp.src[4] = Wout; pp.dst[4] = WTout;
    pp.xv = x_v; pp.xa = x_a; pp.pv = pv; pp.pa = pa;
    prep_kernel<<<dim3(2176), dim3(256), 0, stream>>>(pp);

    FPtrs fp;
    fp.x[0] = x_v; fp.x[1] = x_a;
    fp.WT1[0] = WT1v; fp.WT1[1] = WT1a;
    fp.b1[0] = b1v; fp.b1[1] = b1a;
    fp.pd[0] = pv; fp.pd[1] = pa;
    fp.g1[0] = g1v; fp.g1[1] = g1a;
    fp.WTm[0] = WTmv; fp.WTm[1] = WTma;
    fp.bm[0] = bmv; fp.bm[1] = bma;
    fp.comb = comb;
    fp.WTout = WTout; fp.bout = bout;
    fp.out = out;

    // 2-4) barrier-free wave GEMMs, stream-serialized
    gemm1_kernel<<<dim3(512), dim3(256), 0, stream>>>(fp);
    gemm2_kernel<<<dim3(512), dim3(256), 0, stream>>>(fp);
    gemm3_kernel<<<dim3(256), dim3(256), 0, stream>>>(fp);
}

// Round 9
// 130.597 us; speedup vs baseline: 1.2855x; 1.2855x over previous
//
#include <hip/hip_runtime.h>
#include <math.h>

#define Bsz  2
#define Ntok 256
#define Ddim 512
#define Hdim 2048
#define Mrows 512

typedef __bf16 bf16_8 __attribute__((ext_vector_type(8)));
typedef __bf16 bf16_4 __attribute__((ext_vector_type(4)));
typedef float  f32x4_t __attribute__((ext_vector_type(4)));

// ---------------------------------------------------------------------------
// Prep kernel.
// [0,640):     transpose+cast fp32 [K][N] -> bf16 [N][K], 64x64 tiles
//              (W1v: 256, W1a: 256, Wout: 128 tiles)
// [640,1664):  distance partial sums (j split 4 ways), raw sums
// [1664,1920): zero d_out (1MB) for kernelB atomics; blk 1664 zeroes bc
// ---------------------------------------------------------------------------
struct PrepPtrs {
    const float* src[3];
    __bf16*      dst[3];
    const float* xv;
    const float* xa;
    float*       pv;    // [4][512] raw sums
    float*       pa;    // [4][512]
    float*       out;   // d_out, zeroed
    float*       bc;    // [512] combined bias, zeroed
};

__global__ __launch_bounds__(256) void prep_kernel(PrepPtrs p) {
    __shared__ float tile[64][65];
    __shared__ float red[4][4];

    int blk = blockIdx.x;
    int tid = threadIdx.x;

    if (blk < 640) {
        // ---- transpose+cast, 64x64 tile (structure verified R8) ----
        const int Ks[3]  = {512, 512, 1024};
        const int Ns[3]  = {2048, 2048, 512};
        const int off[4] = {0, 256, 512, 640};
        int mi = 0;
        while (blk >= off[mi + 1]) ++mi;
        int local = blk - off[mi];
        int shift = (mi < 2) ? 5 : 3;          // n-tiles: 32 for W1*, 8 for Wout
        int bx = local & ((1 << shift) - 1);
        int by = local >> shift;
        const float* src = p.src[mi];
        __bf16*      dst = p.dst[mi];
        int K = Ks[mi], N = Ns[mi];
        int n0 = bx << 6, k0 = by << 6;

        int klb = tid >> 4, nl = (tid & 15) << 2;
#pragma unroll
        for (int pass = 0; pass < 4; ++pass) {
            int kl = (pass << 4) + klb;
            float4 v = *(const float4*)&src[(size_t)(k0 + kl) * N + n0 + nl];
            tile[kl][nl + 0] = v.x;
            tile[kl][nl + 1] = v.y;
            tile[kl][nl + 2] = v.z;
            tile[kl][nl + 3] = v.w;
        }
        __syncthreads();
        int nl2 = tid >> 2, kb = (tid & 3) << 2;
#pragma unroll
        for (int pass = 0; pass < 4; ++pass) {
            int kl2 = (pass << 4) + kb;
            bf16_4 o;
#pragma unroll
            for (int i = 0; i < 4; ++i) o[i] = (__bf16)tile[kl2 + i][nl2];
            *(bf16_4*)&dst[(size_t)(n0 + nl2) * K + k0 + kl2] = o;
        }
    } else if (blk < 1664) {
        // ---- distance partials (verified R4-R8) ----
        int bx   = blk - 640;
        int jc   = bx & 3;
        int g    = bx >> 2;
        int role = g >> 7;
        int b    = (g >> 6) & 1;
        int i0   = (g & 63) << 2;
        const float* Q    = role ? p.xa : p.xv;
        const float* S    = role ? p.xv : p.xa;
        float*       outp = role ? p.pa : p.pv;

        int d0 = tid << 1;
        const float* Qb = Q + ((size_t)b * Ntok + i0) * Ddim + d0;
        const float* Sb = S + ((size_t)b * Ntok + (jc << 6)) * Ddim + d0;

        float2 q[4];
#pragma unroll
        for (int r = 0; r < 4; ++r) q[r] = *(const float2*)(Qb + r * Ddim);

        float acc[4] = {0.f, 0.f, 0.f, 0.f};
#pragma unroll 4
        for (int j = 0; j < 64; ++j) {
            float2 s = *(const float2*)(Sb + (size_t)j * Ddim);
#pragma unroll
            for (int r = 0; r < 4; ++r)
                acc[r] += fabsf(q[r].x - s.x) + fabsf(q[r].y - s.y);
        }
        int lane = tid & 63, wv = tid >> 6;
#pragma unroll
        for (int r = 0; r < 4; ++r) {
            float v = acc[r];
#pragma unroll
            for (int off2 = 32; off2; off2 >>= 1) v += __shfl_down(v, off2);
            if (lane == 0) red[wv][r] = v;
        }
        __syncthreads();
        if (tid < 4) {
            float v = red[0][tid] + red[1][tid] + red[2][tid] + red[3][tid];
            outp[jc * Mrows + b * Ntok + i0 + tid] = v;
        }
    } else {
        // ---- zero d_out (+ bc by first block) ----
        int zb = blk - 1664;                   // 0..255
        float4 z4 = {0.f, 0.f, 0.f, 0.f};
        *(float4*)&p.out[((size_t)zb * 256 + tid) * 4] = z4;
        if (zb == 0 && tid < 128) *(float4*)&p.bc[tid * 4] = z4;
    }
}

// ---------------------------------------------------------------------------
// One 64x64 GEMM tile, 2-deep pipelined ping-pong LDS, BK=32 (R7-verified).
// AMODE: 0 = bf16 A ; 1 = fp32 A scaled by mean-dist (scale4 partials)
// BFP32: 0 = bf16 B ; 1 = fp32 B (cast to bf16 at staging)
// OUTM : 1 = bf16 store ; 2 = fp32 atomicAdd
// ---------------------------------------------------------------------------
template <int GELU, int AMODE, int BFP32, int OUTM>
__device__ void gemm_tile(__bf16 (&As)[2][64][40], __bf16 (&Bs)[2][64][40],
                          const void* Aa, int lda, const void* Bv, int ldb,
                          const float* bias, const float* scale4,
                          void* C, int ldc, int Kdim,
                          int m0, int n0, int addBias) {
    const int tid = threadIdx.x;
    const int row = tid >> 2;        // 0..63
    const int kc  = (tid & 3) << 3;  // 0,8,16,24

    const __bf16* Bb  = (const __bf16*)Bv + (size_t)(n0 + row) * ldb + kc;
    const float*  Bf  = (const float*)Bv + (size_t)(n0 + row) * ldb + kc;
    const float*  Af  = (const float*)Aa + (size_t)(m0 + row) * lda + kc;
    const __bf16* Ab  = (const __bf16*)Aa + (size_t)(m0 + row) * lda + kc;
    float s = 1.0f;
    if (AMODE == 1) {
        int m = m0 + row;
        s = (scale4[m] + scale4[Mrows + m] + scale4[2 * Mrows + m] +
             scale4[3 * Mrows + m]) * (1.0f / 256.0f);
    }

    const int wave = tid >> 6, lane = tid & 63;
    const int moff = (wave >> 1) << 5, noff = (wave & 1) << 5;
    const int lrow = lane & 15, quad = lane >> 4;

    struct Stage {
        float4 aF0, aF1, bF0, bF1;
        bf16_8 a8, b8;
    };
    Stage sR, sN;

    auto loadStage = [&](int kt, Stage& st) {
        if (BFP32) {
            st.bF0 = *(const float4*)(Bf + kt);
            st.bF1 = *(const float4*)(Bf + kt + 4);
        } else {
            st.b8 = *(const bf16_8*)(Bb + kt);
        }
        if (AMODE == 1) {
            st.aF0 = *(const float4*)(Af + kt);
            st.aF1 = *(const float4*)(Af + kt + 4);
        } else {
            st.a8 = *(const bf16_8*)(Ab + kt);
        }
    };
    auto storeStage = [&](int buf, const Stage& st) {
        bf16_8 a8, b8;
        if (AMODE == 1) {
            a8[0] = (__bf16)(st.aF0.x * s); a8[1] = (__bf16)(st.aF0.y * s);
            a8[2] = (__bf16)(st.aF0.z * s); a8[3] = (__bf16)(st.aF0.w * s);
            a8[4] = (__bf16)(st.aF1.x * s); a8[5] = (__bf16)(st.aF1.y * s);
            a8[6] = (__bf16)(st.aF1.z * s); a8[7] = (__bf16)(st.aF1.w * s);
        } else {
            a8 = st.a8;
        }
        if (BFP32) {
            b8[0] = (__bf16)st.bF0.x; b8[1] = (__bf16)st.bF0.y;
            b8[2] = (__bf16)st.bF0.z; b8[3] = (__bf16)st.bF0.w;
            b8[4] = (__bf16)st.bF1.x; b8[5] = (__bf16)st.bF1.y;
            b8[6] = (__bf16)st.bF1.z; b8[7] = (__bf16)st.bF1.w;
        } else {
            b8 = st.b8;
        }
        *(bf16_8*)&As[buf][row][kc] = a8;
        *(bf16_8*)&Bs[buf][row][kc] = b8;
    };

    f32x4_t acc00 = {0.f, 0.f, 0.f, 0.f};
    f32x4_t acc01 = {0.f, 0.f, 0.f, 0.f};
    f32x4_t acc10 = {0.f, 0.f, 0.f, 0.f};
    f32x4_t acc11 = {0.f, 0.f, 0.f, 0.f};

    const int nIter = Kdim >> 5;

    loadStage(0, sR);
    storeStage(0, sR);
    if (nIter > 1) loadStage(32, sR);
    __syncthreads();

    for (int it = 0; it < nIter; ++it) {
        const int cur = it & 1;
        bf16_8 a0 = *(const bf16_8*)&As[cur][moff + lrow][quad << 3];
        bf16_8 a1 = *(const bf16_8*)&As[cur][moff + 16 + lrow][quad << 3];
        bf16_8 b0 = *(const bf16_8*)&Bs[cur][noff + lrow][quad << 3];
        bf16_8 b1 = *(const bf16_8*)&Bs[cur][noff + 16 + lrow][quad << 3];
        if (it + 2 < nIter) loadStage((it + 2) << 5, sN);
        acc00 = __builtin_amdgcn_mfma_f32_16x16x32_bf16(a0, b0, acc00, 0, 0, 0);
        acc01 = __builtin_amdgcn_mfma_f32_16x16x32_bf16(a0, b1, acc01, 0, 0, 0);
        acc10 = __builtin_amdgcn_mfma_f32_16x16x32_bf16(a1, b0, acc10, 0, 0, 0);
        acc11 = __builtin_amdgcn_mfma_f32_16x16x32_bf16(a1, b1, acc11, 0, 0, 0);
        if (it + 1 < nIter) {
            storeStage(cur ^ 1, sR);
            sR = sN;
            __syncthreads();
        }
    }

    f32x4_t accs[2][2] = {{acc00, acc01}, {acc10, acc11}};
#pragma unroll
    for (int ti = 0; ti < 2; ++ti) {
#pragma unroll
        for (int tj = 0; tj < 2; ++tj) {
            int colg = n0 + noff + (tj << 4) + lrow;
            float bv = addBias ? bias[colg] : 0.0f;
#pragma unroll
            for (int r = 0; r < 4; ++r) {
                int rowg = m0 + moff + (ti << 4) + (quad << 2) + r;
                float v = accs[ti][tj][r] + bv;
                if (GELU) v = 0.5f * v * (1.0f + erff(v * 0.70710678118654752f));
                if (OUTM == 1)
                    ((__bf16*)C)[(size_t)rowg * ldc + colg] = (__bf16)v;
                else
                    atomicAdd((float*)C + (size_t)rowg * ldc + colg, v);
            }
        }
    }
}

// ---------------------------------------------------------------------------
// kernelA: three independent jobs in one launch (4+ blocks/CU):
//  [0,512):    gemm1  g1[z] = gelu(diag(d)*x[z] @ W1[z] + b1[z])
//  [512,1024): WcT[z] = WToutslice(z) @ Wm[z]   (M=512 nout, N=2048 h, K=512 d)
//              -> WcT[z][nout][h] is exactly the B-layout kernelB needs
//  [1024,1032): bc = bmv@Wout_top + bma@Wout_bot + bout  (GEMV, atomic)
// ---------------------------------------------------------------------------
struct APtrs {
    const float*  x[2];
    const __bf16* WT1[2];    // [2048][512]
    const float*  b1[2];
    const float*  pd[2];     // [4][512]
    __bf16*       g1[2];     // [512][2048]
    const __bf16* WTout;     // [512][1024]
    const float*  Wm[2];     // fp32 [2048][512] native
    const float*  bm[2];
    const float*  Wout;      // fp32 [1024][512] native
    const float*  bout;
    __bf16*       WcT[2];    // [512][2048]
    float*        bc;        // [512], zeroed by prep
};

__global__ __launch_bounds__(256) void kernelA(APtrs p) {
    __shared__ __align__(16) __bf16 As[2][64][40];
    __shared__ __align__(16) __bf16 Bs[2][64][40];
    int blk = blockIdx.x;
    if (blk < 512) {
        int z = blk >> 8, t = blk & 255;
        int mt = t >> 5, nt = t & 31;
        gemm_tile<1, 1, 0, 1>(As, Bs, p.x[z], Ddim, p.WT1[z], Ddim,
                              p.b1[z], p.pd[z], p.g1[z], Hdim, Ddim,
                              mt << 6, nt << 6, 1);
    } else if (blk < 1024) {
        int b2 = blk - 512;
        int z = b2 >> 8, t = b2 & 255;
        int mt = t >> 5, nt = t & 31;
        // A = WTout (+z*512 k-offset), B = Wm[z] fp32, C = WcT[z]
        gemm_tile<0, 0, 1, 1>(As, Bs, p.WTout + z * 512, 2 * Ddim,
                              p.Wm[z], Ddim, nullptr, nullptr,
                              p.WcT[z], Hdim, Ddim, mt << 6, nt << 6, 0);
    } else {
        // bc GEMV: 8 blocks x 128 k-rows
        int kb = blk - 1024;
        int tid = threadIdx.x;
        float a0 = 0.f, a1 = 0.f, a2 = 0.f, a3 = 0.f;
#pragma unroll 4
        for (int kk = 0; kk < 128; kk += 2) {
            int k0 = (kb << 7) + kk, k1 = k0 + 1;
            float bk0 = (k0 < 512) ? p.bm[0][k0] : p.bm[1][k0 - 512];
            float bk1 = (k1 < 512) ? p.bm[0][k1] : p.bm[1][k1 - 512];
            a0 += bk0 * p.Wout[(size_t)k0 * Ddim + tid];
            a1 += bk0 * p.Wout[(size_t)k0 * Ddim + tid + 256];
            a2 += bk1 * p.Wout[(size_t)k1 * Ddim + tid];
            a3 += bk1 * p.Wout[(size_t)k1 * Ddim + tid + 256];
        }
        if (kb == 0) { a0 += p.bout[tid]; a1 += p.bout[tid + 256]; }
        atomicAdd(&p.bc[tid],       a0 + a2);
        atomicAdd(&p.bc[tid + 256], a1 + a3);
    }
}

// ---------------------------------------------------------------------------
// kernelB: out = sum_z g1[z] @ WcT[z]^T + bc.  split-K8: 8n x 8m x 8kz = 512
// blocks x 16 iters; kz -> (z, k-offset); fp32 atomicAdd into zeroed out.
// ---------------------------------------------------------------------------
struct BPtrs {
    const __bf16* g1[2];     // [512][2048]
    const __bf16* WcT[2];    // [512][2048]
    const float*  bc;
    float*        out;       // [512][512] fp32, zeroed by prep
};

__global__ __launch_bounds__(256) void kernelB(BPtrs p) {
    __shared__ __align__(16) __bf16 As[2][64][40];
    __shared__ __align__(16) __bf16 Bs[2][64][40];
    int nt = blockIdx.x & 7, mt = (blockIdx.x >> 3) & 7, kz = blockIdx.x >> 6;
    int z = kz >> 2, koff = (kz & 3) << 9;
    gemm_tile<0, 0, 0, 2>(As, Bs, p.g1[z] + koff, Hdim, p.WcT[z] + koff, Hdim,
                          p.bc, nullptr, p.out, Ddim, Ddim,
                          mt << 6, nt << 6, kz == 0);
}

extern "C" void kernel_launch(void* const* d_in, const int* in_sizes, int n_in,
                              void* d_out, int out_size, void* d_ws, size_t ws_size,
                              hipStream_t stream) {
    const float* x_v  = (const float*)d_in[0];
    const float* x_a  = (const float*)d_in[1];
    const float* W1v  = (const float*)d_in[2];
    const float* b1v  = (const float*)d_in[3];
    const float* W1a  = (const float*)d_in[4];
    const float* b1a  = (const float*)d_in[5];
    const float* Wmv  = (const float*)d_in[6];
    const float* bmv  = (const float*)d_in[7];
    const float* Wma  = (const float*)d_in[8];
    const float* bma  = (const float*)d_in[9];
    const float* Wout = (const float*)d_in[10];
    const float* bout = (const float*)d_in[11];
    float* out = (float*)d_out;

    char* w = (char*)d_ws;
    auto alloc = [&](size_t bytes) {
        char* r = w;
        w += (bytes + 255) & ~(size_t)255;
        return (void*)r;
    };
    float*    pv    = (float*)alloc(4 * Mrows * 4);
    float*    pa    = (float*)alloc(4 * Mrows * 4);
    float*    bc    = (float*)alloc(Ddim * 4);
    __bf16*   WT1v  = (__bf16*)alloc((size_t)Hdim * Ddim * 2);      // [2048][512]
    __bf16*   WT1a  = (__bf16*)alloc((size_t)Hdim * Ddim * 2);
    __bf16*   WTout = (__bf16*)alloc((size_t)Ddim * 2 * Ddim * 2);  // [512][1024]
    __bf16*   WcTv  = (__bf16*)alloc((size_t)Ddim * Hdim * 2);      // [512][2048]
    __bf16*   WcTa  = (__bf16*)alloc((size_t)Ddim * Hdim * 2);
    __bf16*   g1v   = (__bf16*)alloc((size_t)Mrows * Hdim * 2);
    __bf16*   g1a   = (__bf16*)alloc((size_t)Mrows * Hdim * 2);

    // 1) prep: transposes (W1v, W1a, Wout) + dist partials + zero out/bc
    PrepPtrs pp;
    pp.src[0] = W1v;  pp.dst[0] = WT1v;
    pp.src[1] = W1a;  pp.dst[1] = WT1a;
    pp.src[2] = Wout; pp.dst[2] = WTout;
    pp.xv = x_v; pp.xa = x_a; pp.pv = pv; pp.pa = pa;
    pp.out = out; pp.bc = bc;
    prep_kernel<<<dim3(1920), dim3(256), 0, stream>>>(pp);

    // 2) kernelA: gemm1 + WcT-product + bc-GEMV (independent jobs)
    APtrs ap;
    ap.x[0] = x_v; ap.x[1] = x_a;
    ap.WT1[0] = WT1v; ap.WT1[1] = WT1a;
    ap.b1[0] = b1v; ap.b1[1] = b1a;
    ap.pd[0] = pv; ap.pd[1] = pa;
    ap.g1[0] = g1v; ap.g1[1] = g1a;
    ap.WTout = WTout;
    ap.Wm[0] = Wmv; ap.Wm[1] = Wma;
    ap.bm[0] = bmv; ap.bm[1] = bma;
    ap.Wout = Wout; ap.bout = bout;
    ap.WcT[0] = WcTv; ap.WcT[1] = WcTa;
    ap.bc = bc;
    kernelA<<<dim3(1032), dim3(256), 0, stream>>>(ap);

    // 3) kernelB: out = sum_z g1[z] @ WcT[z]^T + bc
    BPtrs bp;
    bp.g1[0] = g1v; bp.g1[1] = g1a;
    bp.WcT[0] = WcTv; bp.WcT[1] = WcTa;
    bp.bc = bc; bp.out = out;
    kernelB<<<dim3(512), dim3(256), 0, stream>>>(bp);
}

// Round 10
// 129.015 us; speedup vs baseline: 1.3013x; 1.0123x over previous
//
#include <hip/hip_runtime.h>
#include <math.h>

#define Bsz  2
#define Ntok 256
#define Ddim 512
#define Hdim 2048
#define Mrows 512

typedef __bf16 bf16_8 __attribute__((ext_vector_type(8)));
typedef __bf16 bf16_4 __attribute__((ext_vector_type(4)));
typedef __bf16 bf16_2 __attribute__((ext_vector_type(2)));
typedef float  f32x4_t __attribute__((ext_vector_type(4)));

// ---------------------------------------------------------------------------
// Prep kernel.
// [0,640):     transpose+cast fp32 [K][N] -> bf16 [N][K], 64x64 tiles
//              (W1v: 256, W1a: 256, Wout: 128 tiles)
// [640,1664):  distance partial sums (j split 4 ways); jc==0 blocks also
//              write bf16 copies of their x rows (for gemm1's A fetch)
// [1664,1672): bc = bmv@Wout_top + bma@Wout_bot + bout (atomic GEMV; bc
//              zeroed by hipMemsetAsync before this launch)
// ---------------------------------------------------------------------------
struct PrepPtrs {
    const float* src[3];
    __bf16*      dst[3];
    const float* xv;
    const float* xa;
    __bf16*      xbf[2];   // bf16 copies of x_v, x_a  [512][512]
    float*       pv;       // [4][512] raw sums
    float*       pa;       // [4][512]
    const float* bm[2];
    const float* Wout;     // fp32 [1024][512] native
    const float* bout;
    float*       bc;       // [512], zeroed by memset
};

__global__ __launch_bounds__(256) void prep_kernel(PrepPtrs p) {
    __shared__ float tile[64][65];
    __shared__ float red[4][4];

    int blk = blockIdx.x;
    int tid = threadIdx.x;

    if (blk < 640) {
        // ---- transpose+cast, 64x64 tile (verified R8/R9) ----
        const int Ks[3]  = {512, 512, 1024};
        const int Ns[3]  = {2048, 2048, 512};
        const int off[4] = {0, 256, 512, 640};
        int mi = 0;
        while (blk >= off[mi + 1]) ++mi;
        int local = blk - off[mi];
        int shift = (mi < 2) ? 5 : 3;
        int bx = local & ((1 << shift) - 1);
        int by = local >> shift;
        const float* src = p.src[mi];
        __bf16*      dst = p.dst[mi];
        int K = Ks[mi], N = Ns[mi];
        int n0 = bx << 6, k0 = by << 6;

        int klb = tid >> 4, nl = (tid & 15) << 2;
#pragma unroll
        for (int pass = 0; pass < 4; ++pass) {
            int kl = (pass << 4) + klb;
            float4 v = *(const float4*)&src[(size_t)(k0 + kl) * N + n0 + nl];
            tile[kl][nl + 0] = v.x;
            tile[kl][nl + 1] = v.y;
            tile[kl][nl + 2] = v.z;
            tile[kl][nl + 3] = v.w;
        }
        __syncthreads();
        int nl2 = tid >> 2, kb = (tid & 3) << 2;
#pragma unroll
        for (int pass = 0; pass < 4; ++pass) {
            int kl2 = (pass << 4) + kb;
            bf16_4 o;
#pragma unroll
            for (int i = 0; i < 4; ++i) o[i] = (__bf16)tile[kl2 + i][nl2];
            *(bf16_4*)&dst[(size_t)(n0 + nl2) * K + k0 + kl2] = o;
        }
    } else if (blk < 1664) {
        // ---- distance partials (verified R4-R9) + x bf16 cast on jc==0 ----
        int bx   = blk - 640;
        int jc   = bx & 3;
        int g    = bx >> 2;
        int role = g >> 7;
        int b    = (g >> 6) & 1;
        int i0   = (g & 63) << 2;
        const float* Q    = role ? p.xa : p.xv;
        const float* S    = role ? p.xv : p.xa;
        float*       outp = role ? p.pa : p.pv;

        int d0 = tid << 1;
        const float* Qb = Q + ((size_t)b * Ntok + i0) * Ddim + d0;
        const float* Sb = S + ((size_t)b * Ntok + (jc << 6)) * Ddim + d0;

        float2 q[4];
#pragma unroll
        for (int r = 0; r < 4; ++r) q[r] = *(const float2*)(Qb + r * Ddim);

        if (jc == 0) {
            // each (role,b,igroup) covers 4 unique rows of x across all 512 d
            __bf16* xb = p.xbf[role];
#pragma unroll
            for (int r = 0; r < 4; ++r) {
                bf16_2 o;
                o[0] = (__bf16)q[r].x;
                o[1] = (__bf16)q[r].y;
                *(bf16_2*)&xb[((size_t)b * Ntok + i0 + r) * Ddim + d0] = o;
            }
        }

        float acc[4] = {0.f, 0.f, 0.f, 0.f};
#pragma unroll 4
        for (int j = 0; j < 64; ++j) {
            float2 s = *(const float2*)(Sb + (size_t)j * Ddim);
#pragma unroll
            for (int r = 0; r < 4; ++r)
                acc[r] += fabsf(q[r].x - s.x) + fabsf(q[r].y - s.y);
        }
        int lane = tid & 63, wv = tid >> 6;
#pragma unroll
        for (int r = 0; r < 4; ++r) {
            float v = acc[r];
#pragma unroll
            for (int off2 = 32; off2; off2 >>= 1) v += __shfl_down(v, off2);
            if (lane == 0) red[wv][r] = v;
        }
        __syncthreads();
        if (tid < 4) {
            float v = red[0][tid] + red[1][tid] + red[2][tid] + red[3][tid];
            outp[jc * Mrows + b * Ntok + i0 + tid] = v;
        }
    } else {
        // ---- bc GEMV: 8 blocks x 128 k-rows, atomic into zeroed bc ----
        int kb = blk - 1664;
        float a0 = 0.f, a1 = 0.f, a2 = 0.f, a3 = 0.f;
#pragma unroll 4
        for (int kk = 0; kk < 128; kk += 2) {
            int k0 = (kb << 7) + kk, k1 = k0 + 1;
            float bk0 = (k0 < 512) ? p.bm[0][k0] : p.bm[1][k0 - 512];
            float bk1 = (k1 < 512) ? p.bm[0][k1] : p.bm[1][k1 - 512];
            a0 += bk0 * p.Wout[(size_t)k0 * Ddim + tid];
            a1 += bk0 * p.Wout[(size_t)k0 * Ddim + tid + 256];
            a2 += bk1 * p.Wout[(size_t)k1 * Ddim + tid];
            a3 += bk1 * p.Wout[(size_t)k1 * Ddim + tid + 256];
        }
        if (kb == 0) { a0 += p.bout[tid]; a1 += p.bout[tid + 256]; }
        atomicAdd(&p.bc[tid],       a0 + a2);
        atomicAdd(&p.bc[tid + 256], a1 + a3);
    }
}

// ---------------------------------------------------------------------------
// One 64x64 GEMM tile, 2-deep pipelined ping-pong LDS, BK=32 (R7/R9-verified).
// AMODE: 0 = bf16 A ; 1 = fp32 A scaled by mean-dist ; 3 = bf16 A scaled
// BFP32: 0 = bf16 B ; 1 = fp32 B (cast to bf16 at staging)
// OUTM : 1 = bf16 store ; 2 = fp32 atomicAdd
// ---------------------------------------------------------------------------
template <int GELU, int AMODE, int BFP32, int OUTM>
__device__ void gemm_tile(__bf16 (&As)[2][64][40], __bf16 (&Bs)[2][64][40],
                          const void* Aa, int lda, const void* Bv, int ldb,
                          const float* bias, const float* scale4,
                          void* C, int ldc, int Kdim,
                          int m0, int n0, int addBias) {
    const int tid = threadIdx.x;
    const int row = tid >> 2;        // 0..63
    const int kc  = (tid & 3) << 3;  // 0,8,16,24

    const __bf16* Bb  = (const __bf16*)Bv + (size_t)(n0 + row) * ldb + kc;
    const float*  Bf  = (const float*)Bv + (size_t)(n0 + row) * ldb + kc;
    const float*  Af  = (const float*)Aa + (size_t)(m0 + row) * lda + kc;
    const __bf16* Ab  = (const __bf16*)Aa + (size_t)(m0 + row) * lda + kc;
    float s = 1.0f;
    if (AMODE == 1 || AMODE == 3) {
        int m = m0 + row;
        s = (scale4[m] + scale4[Mrows + m] + scale4[2 * Mrows + m] +
             scale4[3 * Mrows + m]) * (1.0f / 256.0f);
    }

    const int wave = tid >> 6, lane = tid & 63;
    const int moff = (wave >> 1) << 5, noff = (wave & 1) << 5;
    const int lrow = lane & 15, quad = lane >> 4;

    struct Stage {
        float4 aF0, aF1, bF0, bF1;
        bf16_8 a8, b8;
    };
    Stage sR, sN;

    auto loadStage = [&](int kt, Stage& st) {
        if (BFP32) {
            st.bF0 = *(const float4*)(Bf + kt);
            st.bF1 = *(const float4*)(Bf + kt + 4);
        } else {
            st.b8 = *(const bf16_8*)(Bb + kt);
        }
        if (AMODE == 1) {
            st.aF0 = *(const float4*)(Af + kt);
            st.aF1 = *(const float4*)(Af + kt + 4);
        } else {
            st.a8 = *(const bf16_8*)(Ab + kt);
        }
    };
    auto storeStage = [&](int buf, const Stage& st) {
        bf16_8 a8, b8;
        if (AMODE == 1) {
            a8[0] = (__bf16)(st.aF0.x * s); a8[1] = (__bf16)(st.aF0.y * s);
            a8[2] = (__bf16)(st.aF0.z * s); a8[3] = (__bf16)(st.aF0.w * s);
            a8[4] = (__bf16)(st.aF1.x * s); a8[5] = (__bf16)(st.aF1.y * s);
            a8[6] = (__bf16)(st.aF1.z * s); a8[7] = (__bf16)(st.aF1.w * s);
        } else if (AMODE == 3) {
#pragma unroll
            for (int i = 0; i < 8; ++i)
                a8[i] = (__bf16)((float)st.a8[i] * s);
        } else {
            a8 = st.a8;
        }
        if (BFP32) {
            b8[0] = (__bf16)st.bF0.x; b8[1] = (__bf16)st.bF0.y;
            b8[2] = (__bf16)st.bF0.z; b8[3] = (__bf16)st.bF0.w;
            b8[4] = (__bf16)st.bF1.x; b8[5] = (__bf16)st.bF1.y;
            b8[6] = (__bf16)st.bF1.z; b8[7] = (__bf16)st.bF1.w;
        } else {
            b8 = st.b8;
        }
        *(bf16_8*)&As[buf][row][kc] = a8;
        *(bf16_8*)&Bs[buf][row][kc] = b8;
    };

    f32x4_t acc00 = {0.f, 0.f, 0.f, 0.f};
    f32x4_t acc01 = {0.f, 0.f, 0.f, 0.f};
    f32x4_t acc10 = {0.f, 0.f, 0.f, 0.f};
    f32x4_t acc11 = {0.f, 0.f, 0.f, 0.f};

    const int nIter = Kdim >> 5;

    loadStage(0, sR);
    storeStage(0, sR);
    if (nIter > 1) loadStage(32, sR);
    __syncthreads();

    for (int it = 0; it < nIter; ++it) {
        const int cur = it & 1;
        bf16_8 a0 = *(const bf16_8*)&As[cur][moff + lrow][quad << 3];
        bf16_8 a1 = *(const bf16_8*)&As[cur][moff + 16 + lrow][quad << 3];
        bf16_8 b0 = *(const bf16_8*)&Bs[cur][noff + lrow][quad << 3];
        bf16_8 b1 = *(const bf16_8*)&Bs[cur][noff + 16 + lrow][quad << 3];
        if (it + 2 < nIter) loadStage((it + 2) << 5, sN);
        acc00 = __builtin_amdgcn_mfma_f32_16x16x32_bf16(a0, b0, acc00, 0, 0, 0);
        acc01 = __builtin_amdgcn_mfma_f32_16x16x32_bf16(a0, b1, acc01, 0, 0, 0);
        acc10 = __builtin_amdgcn_mfma_f32_16x16x32_bf16(a1, b0, acc10, 0, 0, 0);
        acc11 = __builtin_amdgcn_mfma_f32_16x16x32_bf16(a1, b1, acc11, 0, 0, 0);
        if (it + 1 < nIter) {
            storeStage(cur ^ 1, sR);
            sR = sN;
            __syncthreads();
        }
    }

    f32x4_t accs[2][2] = {{acc00, acc01}, {acc10, acc11}};
#pragma unroll
    for (int ti = 0; ti < 2; ++ti) {
#pragma unroll
        for (int tj = 0; tj < 2; ++tj) {
            int colg = n0 + noff + (tj << 4) + lrow;
            float bv = addBias ? bias[colg] : 0.0f;
#pragma unroll
            for (int r = 0; r < 4; ++r) {
                int rowg = m0 + moff + (ti << 4) + (quad << 2) + r;
                float v = accs[ti][tj][r] + bv;
                if (GELU) v = 0.5f * v * (1.0f + erff(v * 0.70710678118654752f));
                if (OUTM == 1)
                    ((__bf16*)C)[(size_t)rowg * ldc + colg] = (__bf16)v;
                else
                    atomicAdd((float*)C + (size_t)rowg * ldc + colg, v);
            }
        }
    }
}

// ---------------------------------------------------------------------------
// kernelA: two independent GEMM jobs, 1024 blocks = 4/CU:
//  [0,512):    gemm1  g1[z] = gelu(diag(d)*xbf[z] @ W1[z] + b1[z])
//  [512,1024): WcT[z] = WToutslice(z) @ Wm[z]  (B-layout for kernelB)
// ---------------------------------------------------------------------------
struct APtrs {
    const __bf16* xbf[2];    // [512][512] bf16 (from prep)
    const __bf16* WT1[2];    // [2048][512]
    const float*  b1[2];
    const float*  pd[2];     // [4][512]
    __bf16*       g1[2];     // [512][2048]
    const __bf16* WTout;     // [512][1024]
    const float*  Wm[2];     // fp32 [2048][512] native
    __bf16*       WcT[2];    // [512][2048]
};

__global__ __launch_bounds__(256) void kernelA(APtrs p) {
    __shared__ __align__(16) __bf16 As[2][64][40];
    __shared__ __align__(16) __bf16 Bs[2][64][40];
    int blk = blockIdx.x;
    if (blk < 512) {
        int z = blk >> 8, t = blk & 255;
        int mt = t >> 5, nt = t & 31;
        gemm_tile<1, 3, 0, 1>(As, Bs, p.xbf[z], Ddim, p.WT1[z], Ddim,
                              p.b1[z], p.pd[z], p.g1[z], Hdim, Ddim,
                              mt << 6, nt << 6, 1);
    } else {
        int b2 = blk - 512;
        int z = b2 >> 8, t = b2 & 255;
        int mt = t >> 5, nt = t & 31;
        gemm_tile<0, 0, 1, 1>(As, Bs, p.WTout + z * 512, 2 * Ddim,
                              p.Wm[z], Ddim, nullptr, nullptr,
                              p.WcT[z], Hdim, Ddim, mt << 6, nt << 6, 0);
    }
}

// ---------------------------------------------------------------------------
// kernelB: out = sum_z g1[z] @ WcT[z]^T + bc.  split-K8: 8n x 8m x 8kz = 512
// blocks x 16 iters; fp32 atomicAdd into memset-zeroed out (verified R6-R9).
// ---------------------------------------------------------------------------
struct BPtrs {
    const __bf16* g1[2];     // [512][2048]
    const __bf16* WcT[2];    // [512][2048]
    const float*  bc;
    float*        out;       // [512][512] fp32, zeroed by memset
};

__global__ __launch_bounds__(256) void kernelB(BPtrs p) {
    __shared__ __align__(16) __bf16 As[2][64][40];
    __shared__ __align__(16) __bf16 Bs[2][64][40];
    int nt = blockIdx.x & 7, mt = (blockIdx.x >> 3) & 7, kz = blockIdx.x >> 6;
    int z = kz >> 2, koff = (kz & 3) << 9;
    gemm_tile<0, 0, 0, 2>(As, Bs, p.g1[z] + koff, Hdim, p.WcT[z] + koff, Hdim,
                          p.bc, nullptr, p.out, Ddim, Ddim,
                          mt << 6, nt << 6, kz == 0);
}

extern "C" void kernel_launch(void* const* d_in, const int* in_sizes, int n_in,
                              void* d_out, int out_size, void* d_ws, size_t ws_size,
                              hipStream_t stream) {
    const float* x_v  = (const float*)d_in[0];
    const float* x_a  = (const float*)d_in[1];
    const float* W1v  = (const float*)d_in[2];
    const float* b1v  = (const float*)d_in[3];
    const float* W1a  = (const float*)d_in[4];
    const float* b1a  = (const float*)d_in[5];
    const float* Wmv  = (const float*)d_in[6];
    const float* bmv  = (const float*)d_in[7];
    const float* Wma  = (const float*)d_in[8];
    const float* bma  = (const float*)d_in[9];
    const float* Wout = (const float*)d_in[10];
    const float* bout = (const float*)d_in[11];
    float* out = (float*)d_out;

    char* w = (char*)d_ws;
    auto alloc = [&](size_t bytes) {
        char* r = w;
        w += (bytes + 255) & ~(size_t)255;
        return (void*)r;
    };
    float*    pv    = (float*)alloc(4 * Mrows * 4);
    float*    pa    = (float*)alloc(4 * Mrows * 4);
    float*    bc    = (float*)alloc(Ddim * 4);
    __bf16*   xbfv  = (__bf16*)alloc((size_t)Mrows * Ddim * 2);     // [512][512]
    __bf16*   xbfa  = (__bf16*)alloc((size_t)Mrows * Ddim * 2);
    __bf16*   WT1v  = (__bf16*)alloc((size_t)Hdim * Ddim * 2);      // [2048][512]
    __bf16*   WT1a  = (__bf16*)alloc((size_t)Hdim * Ddim * 2);
    __bf16*   WTout = (__bf16*)alloc((size_t)Ddim * 2 * Ddim * 2);  // [512][1024]
    __bf16*   WcTv  = (__bf16*)alloc((size_t)Ddim * Hdim * 2);      // [512][2048]
    __bf16*   WcTa  = (__bf16*)alloc((size_t)Ddim * Hdim * 2);
    __bf16*   g1v   = (__bf16*)alloc((size_t)Mrows * Hdim * 2);
    __bf16*   g1a   = (__bf16*)alloc((size_t)Mrows * Hdim * 2);

    // 0) async zero of atomic-accumulated buffers (graph-capturable)
    hipMemsetAsync(out, 0, (size_t)Mrows * Ddim * 4, stream);
    hipMemsetAsync(bc, 0, Ddim * 4, stream);

    // 1) prep: transposes + dist partials (+x bf16 cast) + bc GEMV
    PrepPtrs pp;
    pp.src[0] = W1v;  pp.dst[0] = WT1v;
    pp.src[1] = W1a;  pp.dst[1] = WT1a;
    pp.src[2] = Wout; pp.dst[2] = WTout;
    pp.xv = x_v; pp.xa = x_a;
    pp.xbf[0] = xbfv; pp.xbf[1] = xbfa;
    pp.pv = pv; pp.pa = pa;
    pp.bm[0] = bmv; pp.bm[1] = bma;
    pp.Wout = Wout; pp.bout = bout;
    pp.bc = bc;
    prep_kernel<<<dim3(1672), dim3(256), 0, stream>>>(pp);

    // 2) kernelA: gemm1 + WcT product
    APtrs ap;
    ap.xbf[0] = xbfv; ap.xbf[1] = xbfa;
    ap.WT1[0] = WT1v; ap.WT1[1] = WT1a;
    ap.b1[0] = b1v; ap.b1[1] = b1a;
    ap.pd[0] = pv; ap.pd[1] = pa;
    ap.g1[0] = g1v; ap.g1[1] = g1a;
    ap.WTout = WTout;
    ap.Wm[0] = Wmv; ap.Wm[1] = Wma;
    ap.WcT[0] = WcTv; ap.WcT[1] = WcTa;
    kernelA<<<dim3(1024), dim3(256), 0, stream>>>(ap);

    // 3) kernelB: out = sum_z g1[z] @ WcT[z]^T + bc
    BPtrs bp;
    bp.g1[0] = g1v; bp.g1[1] = g1a;
    bp.WcT[0] = WcTv; bp.WcT[1] = WcTa;
    bp.bc = bc; bp.out = out;
    kernelB<<<dim3(512), dim3(256), 0, stream>>>(bp);
}